// Round 1
// baseline (39246.558 us; speedup 1.0000x reference)
//
#include <hip/hip_runtime.h>
#include <hip/hip_bf16.h>

#define B_ 64
#define T_ 1024
#define U_ 256

// ---------------- S = Wq @ Wk^T  (S[d][e] = sum_u Wq[d,u]*Wk[e,u]) ----------------
__global__ __launch_bounds__(256) void k_S(const float* __restrict__ Wq,
                                           const float* __restrict__ Wk,
                                           float* __restrict__ S) {
  int d = blockIdx.x, e = threadIdx.x;
  __shared__ float wq[256];
  wq[e] = Wq[d * 256 + e];
  __syncthreads();
  const float* wk = Wk + (size_t)e * 256;
  float acc = 0.f;
#pragma unroll 8
  for (int u = 0; u < 256; ++u) acc = fmaf(wq[u], wk[u], acc);
  S[d * 256 + e] = acc;
}

// ---------------- z_x[bt][g][o] = sum_d x[bt,d] * kernel[g,d,o]  (bias added later) ----------------
// Tile: 64 bt-rows x 128 o-cols, one gate per blockIdx.z. 256 threads.
template <bool ZX32>
__global__ __launch_bounds__(256) void k_zx(const float* __restrict__ x,
                                            const float* __restrict__ ker,
                                            float* __restrict__ zxf,
                                            __hip_bfloat16* __restrict__ zxh) {
  int tid = threadIdx.x;
  int r0 = blockIdx.x * 64;
  int c0 = blockIdx.y * 128;
  int g = blockIdx.z;
  int tr = tid >> 5;   // 0..7 -> rows tr*8..tr*8+7
  int tc = tid & 31;   // 0..31 -> cols tc*4..tc*4+3
  __shared__ float xs[64][17];
  __shared__ float wt[16][132];
  float4 acc[8];
#pragma unroll
  for (int r = 0; r < 8; ++r) acc[r] = make_float4(0.f, 0.f, 0.f, 0.f);

  for (int kc = 0; kc < 16; ++kc) {
    int k0 = kc * 16;
    {  // stage x: 64x16 floats
      int row = tid >> 2, q4 = tid & 3;
      float4 v = *(const float4*)&x[(size_t)(r0 + row) * 256 + k0 + q4 * 4];
      xs[row][q4 * 4 + 0] = v.x; xs[row][q4 * 4 + 1] = v.y;
      xs[row][q4 * 4 + 2] = v.z; xs[row][q4 * 4 + 3] = v.w;
    }
#pragma unroll
    for (int it = 0; it < 2; ++it) {  // stage w: 16x128 floats
      int i = tid + it * 256;
      int kk = i >> 5, cq = i & 31;
      float4 v = *(const float4*)&ker[((size_t)g * 256 + k0 + kk) * 256 + c0 + cq * 4];
      wt[kk][cq * 4 + 0] = v.x; wt[kk][cq * 4 + 1] = v.y;
      wt[kk][cq * 4 + 2] = v.z; wt[kk][cq * 4 + 3] = v.w;
    }
    __syncthreads();
#pragma unroll
    for (int kk = 0; kk < 16; ++kk) {
      float4 wc = *(const float4*)&wt[kk][tc * 4];
#pragma unroll
      for (int r = 0; r < 8; ++r) {
        float xr = xs[tr * 8 + r][kk];
        acc[r].x = fmaf(xr, wc.x, acc[r].x);
        acc[r].y = fmaf(xr, wc.y, acc[r].y);
        acc[r].z = fmaf(xr, wc.z, acc[r].z);
        acc[r].w = fmaf(xr, wc.w, acc[r].w);
      }
    }
    __syncthreads();
  }
#pragma unroll
  for (int r = 0; r < 8; ++r) {
    size_t bt = (size_t)(r0 + tr * 8 + r);
    size_t zi = (bt * 4 + g) * 256 + c0 + tc * 4;
    if (ZX32) {
      *(float4*)&zxf[zi] = acc[r];
    } else {
      zxh[zi + 0] = __float2bfloat16(acc[r].x);
      zxh[zi + 1] = __float2bfloat16(acc[r].y);
      zxh[zi + 2] = __float2bfloat16(acc[r].z);
      zxh[zi + 3] = __float2bfloat16(acc[r].w);
    }
  }
}

// ---------------- persistent step kernel: 1 block per batch, 1024 threads ----------------
template <bool ZX32>
__global__ __launch_bounds__(1024, 1) void k_step(const float* __restrict__ S,
                                                  const float* __restrict__ RA,
                                                  const float* __restrict__ Wv,
                                                  const float* __restrict__ zxf,
                                                  const __hip_bfloat16* __restrict__ zxh,
                                                  const float* __restrict__ bias,
                                                  float* __restrict__ out) {
  const int b = blockIdx.x;
  const int tid = threadIdx.x;
  const int lane = tid & 63;
  const int w = tid >> 6;   // wave id 0..15
  const int o = tid & 255;  // output index for 256-wide phases

  __shared__ float hh[4][256];         // h ring
  __shared__ float th[4][256];         // t = h@S ring
  __shared__ float vh[4][256];         // v = h@Wv ring
  __shared__ float ebuf[4][256];       // e = attn @ v
  __shared__ float red[16][64][4];     // generic per-wave float4 reduction scratch
  __shared__ float sc[16];             // raw scores
  __shared__ float bs[4][256];         // bias

  // init (all zero-history; matches reference init)
  hh[tid >> 8][o] = 0.f;
  th[tid >> 8][o] = 0.f;
  vh[tid >> 8][o] = 0.f;
  bs[tid >> 8][o] = bias[tid];
  float c = 0.f;  // cell state, owned by threads 0..255
  __syncthreads();

  const size_t zbase = ((size_t)b * T_) * 4 * 256;
  const size_t obase = ((size_t)b * T_) * 256;

  for (int t = 0; t < T_; ++t) {
    // ---- ph1: scores[q][k] = (t_q . h_k) / sqrt(U); wave w handles pair p=w ----
    {
      int q = w >> 2, k = w & 3;
      int rq = (t - 1 - q) & 3, rk = (t - 1 - k) & 3;
      float s = 0.f;
#pragma unroll
      for (int j = 0; j < 4; ++j)
        s = fmaf(th[rq][lane + 64 * j], hh[rk][lane + 64 * j], s);
#pragma unroll
      for (int off = 32; off; off >>= 1) s += __shfl_xor(s, off);
      if (lane == 0) sc[w] = s * 0.0625f;
    }
    __syncthreads();

    // ---- ph2: inline softmax (per-thread, row q) + e[q][o] = sum_k attn * v_k ----
    {
      int q = tid >> 8;
      float s0 = sc[q * 4 + 0], s1 = sc[q * 4 + 1], s2 = sc[q * 4 + 2], s3 = sc[q * 4 + 3];
      float mx = fmaxf(fmaxf(s0, s1), fmaxf(s2, s3));
      float e0 = __expf(s0 - mx), e1 = __expf(s1 - mx), e2 = __expf(s2 - mx), e3 = __expf(s3 - mx);
      float inv = 1.f / (e0 + e1 + e2 + e3);
      int r0 = (t - 1) & 3, r1 = (t - 2) & 3, r2 = (t - 3) & 3, r3 = (t - 4) & 3;
      ebuf[q][o] = (e0 * vh[r0][o] + e1 * vh[r1][o] + e2 * vh[r2][o] + e3 * vh[r3][o]) * inv;
    }
    __syncthreads();

    // ---- ph3: z_rec partials: thread (g, q, quad=lane) does 256-d strip of e_q @ RA[g,q] ----
    {
      int g = tid >> 8, q = (tid >> 6) & 3;
      const float* rp = RA + (((size_t)g * 1024) + q * 256) * 256 + lane * 4;
      float a0 = 0.f, a1 = 0.f, a2 = 0.f, a3 = 0.f;
#pragma unroll 8
      for (int m = 0; m < 256; ++m) {
        float ev = ebuf[q][m];
        float4 rv = *(const float4*)(rp + (size_t)m * 256);
        a0 = fmaf(ev, rv.x, a0); a1 = fmaf(ev, rv.y, a1);
        a2 = fmaf(ev, rv.z, a2); a3 = fmaf(ev, rv.w, a3);
      }
      *(float4*)&red[w][lane][0] = make_float4(a0, a1, a2, a3);
    }
    __syncthreads();

    // ---- ph4: combine z, gates, state update (threads 0..255) ----
    if (tid < 256) {
      float z[4];
#pragma unroll
      for (int g = 0; g < 4; ++g) {
        float zz = bs[g][o];
        size_t zi = zbase + ((size_t)t * 4 + g) * 256 + o;
        zz += ZX32 ? zxf[zi] : __bfloat162float(zxh[zi]);
#pragma unroll
        for (int q = 0; q < 4; ++q) zz += red[g * 4 + q][o >> 2][o & 3];
        z[g] = zz;
      }
      float fg = 1.f / (1.f + __expf(-z[0]));
      float ig = 1.f / (1.f + __expf(-z[1]));
      float og = 1.f / (1.f + __expf(-z[2]));
      float ch = tanhf(z[3]);
      c = fmaf(fg, c, ig * ch);
      float ho = og * tanhf(c);
      out[obase + (size_t)t * 256 + o] = ho;
      hh[t & 3][o] = ho;
    }
    __syncthreads();

    // ---- ph5: t_new = h@S, v_new = h@Wv; d-split 8-way, balanced over 16 waves ----
    {
      int hr = t & 3;
      int mat = tid >> 9;         // 0: S, 1: Wv
      int seg = (tid >> 6) & 7;   // 8 d-segments of 32
      const float* Wp = (mat ? Wv : S) + ((size_t)(seg * 32)) * 256 + lane * 4;
      float a0 = 0.f, a1 = 0.f, a2 = 0.f, a3 = 0.f;
#pragma unroll 4
      for (int dd = 0; dd < 32; ++dd) {
        float hd = hh[hr][seg * 32 + dd];
        float4 wv4 = *(const float4*)(Wp + (size_t)dd * 256);
        a0 = fmaf(hd, wv4.x, a0); a1 = fmaf(hd, wv4.y, a1);
        a2 = fmaf(hd, wv4.z, a2); a3 = fmaf(hd, wv4.w, a3);
      }
      *(float4*)&red[w][lane][0] = make_float4(a0, a1, a2, a3);
    }
    __syncthreads();

    // ---- ph5b: reduce 8 segments -> write th / vh ----
    if (tid < 512) {
      int mat = tid >> 8, oo = tid & 255;
      float s = 0.f;
#pragma unroll
      for (int seg = 0; seg < 8; ++seg) s += red[mat * 8 + seg][oo >> 2][oo & 3];
      (mat ? vh : th)[t & 3][oo] = s;
    }
    __syncthreads();
  }
}

extern "C" void kernel_launch(void* const* d_in, const int* in_sizes, int n_in,
                              void* d_out, int out_size, void* d_ws, size_t ws_size,
                              hipStream_t stream) {
  const float* x    = (const float*)d_in[0];
  const float* ker  = (const float*)d_in[1];
  const float* ra   = (const float*)d_in[2];
  const float* bias = (const float*)d_in[3];
  const float* wq   = (const float*)d_in[4];
  const float* wk   = (const float*)d_in[5];
  const float* wv   = (const float*)d_in[6];
  float* out = (float*)d_out;

  char* ws = (char*)d_ws;
  float* S = (float*)ws;                      // 256 KB
  const size_t ZOFF = 262144;
  float* zxf = (float*)(ws + ZOFF);           // fp32 z_x: 268 MB
  __hip_bfloat16* zxh = (__hip_bfloat16*)(ws + ZOFF);  // bf16 fallback: 134 MB

  // constant across calls -> graph-safe branch
  bool zx32 = (ws_size >= ZOFF + (size_t)B_ * T_ * 4 * U_ * 4);

  k_S<<<256, 256, 0, stream>>>(wq, wk, S);
  if (zx32) {
    k_zx<true><<<dim3(1024, 2, 4), 256, 0, stream>>>(x, ker, zxf, zxh);
    k_step<true><<<64, 1024, 0, stream>>>(S, ra, wv, zxf, zxh, bias, out);
  } else {
    k_zx<false><<<dim3(1024, 2, 4), 256, 0, stream>>>(x, ker, zxf, zxh);
    k_step<false><<<64, 1024, 0, stream>>>(S, ra, wv, zxf, zxh, bias, out);
  }
}